// Round 8
// baseline (325.555 us; speedup 1.0000x reference)
//
#include <hip/hip_runtime.h>
#include <hip/hip_bf16.h>
#include <math.h>

#define DIMC   1024
#define NHEADS 16
#define HDIM   64
#define BATCH  2
#define SEQ    2048
#define SCALE  0.125f

typedef unsigned short u16;
typedef __attribute__((ext_vector_type(8))) short bf16x8;   // 8 bf16 = 4 VGPRs
typedef __attribute__((ext_vector_type(4))) float f32x4;

// [B][H][N][D] per tensor, element count
#define BHND ((size_t)BATCH * NHEADS * SEQ * HDIM)   // 4,194,304
#define MROWS ((size_t)BATCH * SEQ)                  // 4096

__device__ __forceinline__ u16 f2bf(float x) {
    __hip_bfloat16 h = __float2bfloat16(x);
    return *reinterpret_cast<u16*>(&h);
}
__device__ __forceinline__ float bf2f(u16 x) {
    unsigned int u = ((unsigned int)x) << 16;
    return __uint_as_float(u);
}
__device__ __forceinline__ void gload_lds16(const u16* g, u16* l) {
    __builtin_amdgcn_global_load_lds(
        (const __attribute__((address_space(1))) unsigned int*)g,
        (__attribute__((address_space(3))) unsigned int*)l, 16, 0, 0);
}

// ---------------------------------------------------------------------------
// Prepass 1: elementwise split fp32 -> bf16 hi + lo  (hi+lo ~= x to 2^-17)
// ---------------------------------------------------------------------------
__global__ __launch_bounds__(256) void splita_kernel(
    const float* __restrict__ in, u16* __restrict__ hi, u16* __restrict__ lo)
{
    int i = (blockIdx.x * 256 + threadIdx.x) * 8;
    float4 a = *(const float4*)&in[i];
    float4 b = *(const float4*)&in[i + 4];
    float v[8] = {a.x, a.y, a.z, a.w, b.x, b.y, b.z, b.w};
    bf16x8 vh, vl;
    #pragma unroll
    for (int j = 0; j < 8; ++j) {
        u16 h = f2bf(v[j]);
        vh[j] = (short)h;
        vl[j] = (short)f2bf(v[j] - bf2f(h));
    }
    *(bf16x8*)&hi[i] = vh;
    *(bf16x8*)&lo[i] = vl;
}

// ---------------------------------------------------------------------------
// Prepass 2: W [K][N] fp32 -> transposed split bf16  Thi/Tlo [N][K]
// ---------------------------------------------------------------------------
__global__ __launch_bounds__(256) void splitw_kernel(
    const float* __restrict__ W, u16* __restrict__ Thi, u16* __restrict__ Tlo,
    int K, int N)
{
    __shared__ float Ws[64][65];
    const int kb  = blockIdx.x * 64;
    const int nb  = blockIdx.y * 64;
    const int tid = threadIdx.x;
    const int jr  = (tid & 15) * 4;
    const int ir  = tid >> 4;
    #pragma unroll
    for (int it = 0; it < 4; ++it) {
        int i = ir + it * 16;
        *(float4*)&Ws[i][jr] = *(const float4*)&W[(size_t)(kb + i) * N + nb + jr];
    }
    __syncthreads();
    const int n  = tid >> 2;
    const int k0 = (tid & 3) * 16;
    bf16x8 h0, h1, l0, l1;
    #pragma unroll
    for (int kk = 0; kk < 8; ++kk) {
        float x = Ws[k0 + kk][n];
        u16 h = f2bf(x);
        h0[kk] = (short)h; l0[kk] = (short)f2bf(x - bf2f(h));
        float y = Ws[k0 + 8 + kk][n];
        u16 h2 = f2bf(y);
        h1[kk] = (short)h2; l1[kk] = (short)f2bf(y - bf2f(h2));
    }
    size_t off = (size_t)(nb + n) * K + kb + k0;
    *(bf16x8*)&Thi[off]     = h0;
    *(bf16x8*)&Thi[off + 8] = h1;
    *(bf16x8*)&Tlo[off]     = l0;
    *(bf16x8*)&Tlo[off + 8] = l1;
}

// ---------------------------------------------------------------------------
// Split-bf16 MFMA GEMM (validated round 6). 128x128 tile, BK=32,
// 4 waves x (64x64), global_load_lds staging, 3 MFMAs per fragment pair.
// MODE 0: scatter bf16 q(*SCALE)/k [B][H][N][D], v^T [B][H][D][N]
// MODE 1: + bias, fp32 store to out[M][N]
// ---------------------------------------------------------------------------
template <int MODE>
__global__ __launch_bounds__(256) void gemm_split_kernel(
    const u16* __restrict__ Ahi, const u16* __restrict__ Alo,
    const u16* __restrict__ Bhi, const u16* __restrict__ Blo,
    const float* __restrict__ bias,
    float* __restrict__ outf, u16* __restrict__ outb,
    int M, int N, int K)
{
    __shared__ __align__(16) u16 lds[4][128 * 32];   // Ahi, Alo, BhiT, BloT

    const int bm   = blockIdx.y * 128;
    const int bn   = blockIdx.x * 128;
    const int tid  = threadIdx.x;
    const int wid  = tid >> 6;
    const int lane = tid & 63;
    const int lo   = lane & 15;
    const int g4   = lane >> 4;
    const int wr   = wid >> 1, wc = wid & 1;

    const int mrow = lane >> 2;
    const int ks8  = (lane & 3) * 8;
    const u16* g0;
    if      (wid == 0) g0 = Ahi + (size_t)(bm + mrow) * K + ks8;
    else if (wid == 1) g0 = Alo + (size_t)(bm + mrow) * K + ks8;
    else if (wid == 2) g0 = Bhi + (size_t)(bn + mrow) * K + ks8;
    else               g0 = Blo + (size_t)(bn + mrow) * K + ks8;
    u16* lbase = &lds[wid][0];

    f32x4 acc[4][4] = {};

    for (int k0 = 0; k0 < K; k0 += 32) {
        const u16* g = g0 + k0;
        #pragma unroll
        for (int s = 0; s < 8; ++s)
            gload_lds16(g + (size_t)s * 16 * K, lbase + s * 512);
        __syncthreads();

        bf16x8 bh[4], bl[4];
        #pragma unroll
        for (int ni = 0; ni < 4; ++ni) {
            int row = wc * 64 + ni * 16 + lo;
            bh[ni] = *(const bf16x8*)&lds[2][row * 32 + g4 * 8];
            bl[ni] = *(const bf16x8*)&lds[3][row * 32 + g4 * 8];
        }
        #pragma unroll
        for (int mi = 0; mi < 4; ++mi) {
            int row = wr * 64 + mi * 16 + lo;
            bf16x8 ah = *(const bf16x8*)&lds[0][row * 32 + g4 * 8];
            bf16x8 al = *(const bf16x8*)&lds[1][row * 32 + g4 * 8];
            #pragma unroll
            for (int ni = 0; ni < 4; ++ni) {
                acc[mi][ni] = __builtin_amdgcn_mfma_f32_16x16x32_bf16(ah, bh[ni], acc[mi][ni], 0, 0, 0);
                acc[mi][ni] = __builtin_amdgcn_mfma_f32_16x16x32_bf16(ah, bl[ni], acc[mi][ni], 0, 0, 0);
                acc[mi][ni] = __builtin_amdgcn_mfma_f32_16x16x32_bf16(al, bh[ni], acc[mi][ni], 0, 0, 0);
            }
        }
        __syncthreads();
    }

    if (MODE == 0) {
        #pragma unroll
        for (int mi = 0; mi < 4; ++mi) {
            int m0 = bm + wr * 64 + mi * 16 + 4 * g4;
            #pragma unroll
            for (int ni = 0; ni < 4; ++ni) {
                int n0    = bn + wc * 64 + ni * 16;
                int which = n0 >> 10;
                int head  = (n0 & 1023) >> 6;
                int d     = (n0 & 63) + lo;
                if (which == 0) {
                    #pragma unroll
                    for (int r = 0; r < 4; ++r) {
                        int m = m0 + r, b = m >> 11, seq = m & 2047;
                        outb[(((size_t)b * NHEADS + head) * SEQ + seq) * HDIM + d] =
                            f2bf(acc[mi][ni][r] * SCALE);
                    }
                } else if (which == 1) {
                    #pragma unroll
                    for (int r = 0; r < 4; ++r) {
                        int m = m0 + r, b = m >> 11, seq = m & 2047;
                        outb[BHND + (((size_t)b * NHEADS + head) * SEQ + seq) * HDIM + d] =
                            f2bf(acc[mi][ni][r]);
                    }
                } else {
                    int b = m0 >> 11, seq0 = m0 & 2047;
                    ushort4 o;
                    o.x = f2bf(acc[mi][ni][0]); o.y = f2bf(acc[mi][ni][1]);
                    o.z = f2bf(acc[mi][ni][2]); o.w = f2bf(acc[mi][ni][3]);
                    *(ushort4*)&outb[2 * BHND +
                        (((size_t)b * NHEADS + head) * HDIM + d) * SEQ + seq0] = o;
                }
            }
        }
    } else {
        #pragma unroll
        for (int ni = 0; ni < 4; ++ni) {
            int col = bn + wc * 64 + ni * 16 + lo;
            float bv = bias[col];
            #pragma unroll
            for (int mi = 0; mi < 4; ++mi) {
                int m0 = bm + wr * 64 + mi * 16 + 4 * g4;
                #pragma unroll
                for (int r = 0; r < 4; ++r)
                    outf[(size_t)(m0 + r) * N + col] = acc[mi][ni][r] + bv;
            }
        }
    }
}

// ---------------------------------------------------------------------------
// MFMA flash attention with in-kernel split-KV.
// Block = 32 q-rows, 4 waves: wave = (qsub = wid&1) x (khalf = wid>>1).
// Each wave sweeps 1024 keys (32-key tiles, validated round-4 inner math).
// Grid doubles to 2048 blocks (TLP for latency hiding); key-halves merge
// exactly in fp32 via LDS (reusing K-tile space) before the epilogue.
// Pad-based bank-conflict avoidance: K rows stride 72 u16, V^T rows 40 u16.
// ---------------------------------------------------------------------------
__global__ __launch_bounds__(256) void attn_mfma_kernel(
    const u16* __restrict__ qb, const u16* __restrict__ kb,
    const u16* __restrict__ vtb, const float* __restrict__ mask,
    u16* __restrict__ ohi, u16* __restrict__ olo)
{
    __shared__ __align__(16) u16 Ks[2][32 * 72];    // [khalf][key][d], pad 72
    __shared__ __align__(16) u16 Vt[2][64 * 40];    // [khalf][d][key], pad 40
    __shared__ __align__(16) u16 Plds[4][16 * 40];
    __shared__ float Ms[2][32];

    const int bid  = blockIdx.x;          // 2048 = B*H*(SEQ/32)
    const int qt   = bid & 63;
    const int h    = (bid >> 6) & 15;
    const int b    = bid >> 10;
    const int tid  = threadIdx.x;
    const int wid  = tid >> 6;
    const int lane = tid & 63;
    const int lo   = lane & 15;
    const int g    = lane >> 4;
    const int qsub  = wid & 1;
    const int khalf = wid >> 1;

    const size_t bh = (size_t)b * NHEADS + h;
    const int qbase = qt * 32 + qsub * 16;

    // Q A-frags: row = qbase+lo, kdim = ks*32 + 8g + j  (held all kernel)
    const u16* qrowp = qb + (bh * SEQ + qbase + lo) * HDIM + 8 * g;
    const bf16x8 aq0 = *(const bf16x8*)(qrowp);
    const bf16x8 aq1 = *(const bf16x8*)(qrowp + 32);

    // staging maps (all 4 waves stage both halves, coalesced)
    const int srow = tid >> 2;            // 0..63
    const int khs  = srow >> 5;           // which half this thread stages (K)
    const int krow = srow & 31;
    const int scol = (tid & 3) * 16;
    const u16* kgp = kb + (bh * SEQ + (size_t)khs * 1024 + krow) * HDIM + scol;
    u16* kld = &Ks[khs][krow * 72 + scol];

    const int vhs  = tid >> 7;            // which half this thread stages (V)
    const int vrow = (tid >> 1) & 63;     // d
    const int vseg = (tid & 1) * 16;
    const u16* vgp = vtb + (bh * HDIM + vrow) * SEQ + (size_t)vhs * 1024 + vseg;
    u16* vld = &Vt[vhs][vrow * 40 + vseg];

    f32x4 acc[4] = {};
    float mrun[4], lrun[4];
    #pragma unroll
    for (int r = 0; r < 4; ++r) { mrun[r] = -1e30f; lrun[r] = 0.f; }

    u16* pw = &Plds[wid][0];
    const u16* Kh = &Ks[khalf][0];
    const u16* Vh = &Vt[khalf][0];

    for (int k0 = 0; k0 < SEQ / 2; k0 += 32) {
        __syncthreads();
        *(bf16x8*)(kld)     = *(const bf16x8*)(kgp + (size_t)k0 * HDIM);
        *(bf16x8*)(kld + 8) = *(const bf16x8*)(kgp + (size_t)k0 * HDIM + 8);
        *(bf16x8*)(vld)     = *(const bf16x8*)(vgp + k0);
        *(bf16x8*)(vld + 8) = *(const bf16x8*)(vgp + k0 + 8);
        if (tid < 64)
            Ms[tid >> 5][tid & 31] =
                mask[b * SEQ + (tid >> 5) * 1024 + k0 + (tid & 31)];
        __syncthreads();

        // QK^T: S[16q x 32key]  (q pre-scaled by SCALE in the qkv GEMM)
        f32x4 s0 = {}, s1 = {};
        s0 = __builtin_amdgcn_mfma_f32_16x16x32_bf16(aq0, *(const bf16x8*)&Kh[lo * 72 + 8 * g], s0, 0, 0, 0);
        s0 = __builtin_amdgcn_mfma_f32_16x16x32_bf16(aq1, *(const bf16x8*)&Kh[lo * 72 + 32 + 8 * g], s0, 0, 0, 0);
        s1 = __builtin_amdgcn_mfma_f32_16x16x32_bf16(aq0, *(const bf16x8*)&Kh[(lo + 16) * 72 + 8 * g], s1, 0, 0, 0);
        s1 = __builtin_amdgcn_mfma_f32_16x16x32_bf16(aq1, *(const bf16x8*)&Kh[(lo + 16) * 72 + 32 + 8 * g], s1, 0, 0, 0);

        // online softmax, UNMASKED denominator; bit-exact skip-rescale
        float p0v[4], p1v[4];
        #pragma unroll
        for (int r = 0; r < 4; ++r) {
            float rm = fmaxf(s0[r], s1[r]);
            rm = fmaxf(rm, __shfl_xor(rm, 1));
            rm = fmaxf(rm, __shfl_xor(rm, 2));
            rm = fmaxf(rm, __shfl_xor(rm, 4));
            rm = fmaxf(rm, __shfl_xor(rm, 8));
            if (!__all(rm <= mrun[r])) {
                float mnew = fmaxf(mrun[r], rm);
                float corr = __expf(mrun[r] - mnew);
                mrun[r] = mnew;
                lrun[r] *= corr;
                #pragma unroll
                for (int dt = 0; dt < 4; ++dt) acc[dt][r] *= corr;
            }
            float p0 = __expf(s0[r] - mrun[r]);
            float p1 = __expf(s1[r] - mrun[r]);
            float ps = p0 + p1;
            ps += __shfl_xor(ps, 1);
            ps += __shfl_xor(ps, 2);
            ps += __shfl_xor(ps, 4);
            ps += __shfl_xor(ps, 8);
            lrun[r] += ps;
            p0v[r] = p0; p1v[r] = p1;
        }

        // masked numerator -> P in LDS (A-frag layout for PV)
        const float mv0 = Ms[khalf][lo], mv1 = Ms[khalf][lo + 16];
        #pragma unroll
        for (int r = 0; r < 4; ++r) {
            pw[(4 * g + r) * 40 + lo]      = f2bf(p0v[r] * mv0);
            pw[(4 * g + r) * 40 + lo + 16] = f2bf(p1v[r] * mv1);
        }

        // PV: O += P[16,32] @ V[32,64]  (same-wave DS ops are in-order)
        const bf16x8 pa = *(const bf16x8*)&pw[lo * 40 + 8 * g];
        #pragma unroll
        for (int dt = 0; dt < 4; ++dt) {
            const bf16x8 bv = *(const bf16x8*)&Vh[(lo + 16 * dt) * 40 + 8 * g];
            acc[dt] = __builtin_amdgcn_mfma_f32_16x16x32_bf16(pa, bv, acc[dt], 0, 0, 0);
        }
    }

    // ---- exact fp32 combine of the two key-halves (LDS reuse) ----
    __syncthreads();                       // all waves done reading Ks/Vt
    float* X  = (float*)&Ks[0][0];         // 2 qsubs x 64 lanes x 16 = 8 KB
    float* ML = (float*)&Vt[0][0];         // 2 qsubs x 16 rows x {m,l}
    if (khalf == 1) {
        int base = qsub * 1024 + lane * 16;
        #pragma unroll
        for (int dt = 0; dt < 4; ++dt)
            #pragma unroll
            for (int r = 0; r < 4; ++r)
                X[base + dt * 4 + r] = acc[dt][r];
        if (lo == 0) {
            #pragma unroll
            for (int r = 0; r < 4; ++r) {
                ML[qsub * 32 + (4 * g + r) * 2]     = mrun[r];
                ML[qsub * 32 + (4 * g + r) * 2 + 1] = lrun[r];
            }
        }
    }
    __syncthreads();
    if (khalf == 0) {
        int base = qsub * 1024 + lane * 16;
        #pragma unroll
        for (int r = 0; r < 4; ++r) {
            float m1 = ML[qsub * 32 + (4 * g + r) * 2];
            float l1 = ML[qsub * 32 + (4 * g + r) * 2 + 1];
            float M  = fmaxf(mrun[r], m1);
            float c0 = __expf(mrun[r] - M);
            float c1 = __expf(m1 - M);
            float inv = 1.f / (lrun[r] * c0 + l1 * c1);
            size_t row = (size_t)b * SEQ + qbase + 4 * g + r;
            u16* dh = ohi + row * DIMC + h * HDIM + lo;
            u16* dl = olo + row * DIMC + h * HDIM + lo;
            #pragma unroll
            for (int dt = 0; dt < 4; ++dt) {
                float o = (acc[dt][r] * c0 + X[base + dt * 4 + r] * c1) * inv;
                u16 hv = f2bf(o);
                dh[16 * dt] = hv;
                dl[16 * dt] = f2bf(o - bf2f(hv));
            }
        }
    }
}

__global__ void mask_sqrt_kernel(const float* __restrict__ mask,
                                 float* __restrict__ out, int n)
{
    int i = blockIdx.x * 256 + threadIdx.x;
    if (i < n) out[i] = sqrtf(mask[i]);
}

// ---------------------------------------------------------------------------
extern "C" void kernel_launch(void* const* d_in, const int* in_sizes, int n_in,
                              void* d_out, int out_size, void* d_ws, size_t ws_size,
                              hipStream_t stream)
{
    const float* h      = (const float*)d_in[0];   // [2,2048,1024]
    const float* mask   = (const float*)d_in[1];   // [2,2048]
    const float* w_qkv  = (const float*)d_in[2];   // [1024,3072]
    const float* w_proj = (const float*)d_in[3];   // [1024,1024]
    const float* b_proj = (const float*)d_in[4];   // [1024]
    float* out = (float*)d_out;

    // ws layout (u16 units), ~59 MB total
    u16* w    = (u16*)d_ws;
    u16* qkv  = w;                                  // 3*BHND
    u16* wqh  = qkv + 3 * BHND;                     // 3072*1024
    u16* wql  = wqh + (size_t)3072 * 1024;
    u16* wph  = wql + (size_t)3072 * 1024;          // 1024*1024
    u16* wpl  = wph + (size_t)1024 * 1024;
    u16* ahi  = wpl + (size_t)1024 * 1024;          // 4096*1024 (h split; later O split)
    u16* alo  = ahi + MROWS * DIMC;

    // prepasses: split h; split+transpose weights
    splita_kernel<<<(MROWS * DIMC) / (256 * 8), 256, 0, stream>>>(h, ahi, alo);
    splitw_kernel<<<dim3(16, 48), 256, 0, stream>>>(w_qkv, wqh, wql, DIMC, 3 * DIMC);
    splitw_kernel<<<dim3(16, 16), 256, 0, stream>>>(w_proj, wph, wpl, DIMC, DIMC);

    // 1) qkv projection (split MFMA) -> bf16 q(scaled)/k [B][H][N][D], v^T [B][H][D][N]
    gemm_split_kernel<0><<<dim3(24, 32), 256, 0, stream>>>(
        ahi, alo, wqh, wql, nullptr, nullptr, qkv, MROWS, 3 * DIMC, DIMC);

    // 2) MFMA flash attention, in-kernel split-KV (grid 2048)
    attn_mfma_kernel<<<BATCH * NHEADS * (SEQ / 32), 256, 0, stream>>>(
        qkv, qkv + BHND, qkv + 2 * BHND, mask, ahi, alo);

    // 3) output projection + bias (split MFMA, fp32 out)
    gemm_split_kernel<1><<<dim3(8, 32), 256, 0, stream>>>(
        ahi, alo, wph, wpl, b_proj, out, nullptr, MROWS, DIMC, DIMC);

    // 4) new_mask = sqrt(mask)
    mask_sqrt_kernel<<<(BATCH * SEQ + 255) / 256, 256, 0, stream>>>(
        mask, out + MROWS * DIMC, BATCH * SEQ);
}

// Round 9
// 219.522 us; speedup vs baseline: 1.4830x; 1.4830x over previous
//
#include <hip/hip_runtime.h>
#include <hip/hip_bf16.h>
#include <math.h>

#define DIMC   1024
#define NHEADS 16
#define HDIM   64
#define BATCH  2
#define SEQ    2048
#define SCALE  0.125f

typedef unsigned short u16;
typedef __attribute__((ext_vector_type(8))) short bf16x8;   // 8 bf16 = 4 VGPRs
typedef __attribute__((ext_vector_type(4))) float f32x4;

// [B][H][N][D] per tensor, element count
#define BHND ((size_t)BATCH * NHEADS * SEQ * HDIM)   // 4,194,304
#define MROWS ((size_t)BATCH * SEQ)                  // 4096

__device__ __forceinline__ u16 f2bf(float x) {
    __hip_bfloat16 h = __float2bfloat16(x);
    return *reinterpret_cast<u16*>(&h);
}
__device__ __forceinline__ float bf2f(u16 x) {
    unsigned int u = ((unsigned int)x) << 16;
    return __uint_as_float(u);
}
__device__ __forceinline__ void gload_lds16(const u16* g, u16* l) {
    __builtin_amdgcn_global_load_lds(
        (const __attribute__((address_space(1))) unsigned int*)g,
        (__attribute__((address_space(3))) unsigned int*)l, 16, 0, 0);
}

// ---------------------------------------------------------------------------
// Prepass 1: elementwise split fp32 -> bf16 hi + lo  (hi+lo ~= x to 2^-17)
// ---------------------------------------------------------------------------
__global__ __launch_bounds__(256) void splita_kernel(
    const float* __restrict__ in, u16* __restrict__ hi, u16* __restrict__ lo)
{
    int i = (blockIdx.x * 256 + threadIdx.x) * 8;
    float4 a = *(const float4*)&in[i];
    float4 b = *(const float4*)&in[i + 4];
    float v[8] = {a.x, a.y, a.z, a.w, b.x, b.y, b.z, b.w};
    bf16x8 vh, vl;
    #pragma unroll
    for (int j = 0; j < 8; ++j) {
        u16 h = f2bf(v[j]);
        vh[j] = (short)h;
        vl[j] = (short)f2bf(v[j] - bf2f(h));
    }
    *(bf16x8*)&hi[i] = vh;
    *(bf16x8*)&lo[i] = vl;
}

// ---------------------------------------------------------------------------
// Prepass 2: W [K][N] fp32 -> transposed split bf16  Thi/Tlo [N][K]
// ---------------------------------------------------------------------------
__global__ __launch_bounds__(256) void splitw_kernel(
    const float* __restrict__ W, u16* __restrict__ Thi, u16* __restrict__ Tlo,
    int K, int N)
{
    __shared__ float Ws[64][65];
    const int kb  = blockIdx.x * 64;
    const int nb  = blockIdx.y * 64;
    const int tid = threadIdx.x;
    const int jr  = (tid & 15) * 4;
    const int ir  = tid >> 4;
    #pragma unroll
    for (int it = 0; it < 4; ++it) {
        int i = ir + it * 16;
        *(float4*)&Ws[i][jr] = *(const float4*)&W[(size_t)(kb + i) * N + nb + jr];
    }
    __syncthreads();
    const int n  = tid >> 2;
    const int k0 = (tid & 3) * 16;
    bf16x8 h0, h1, l0, l1;
    #pragma unroll
    for (int kk = 0; kk < 8; ++kk) {
        float x = Ws[k0 + kk][n];
        u16 h = f2bf(x);
        h0[kk] = (short)h; l0[kk] = (short)f2bf(x - bf2f(h));
        float y = Ws[k0 + 8 + kk][n];
        u16 h2 = f2bf(y);
        h1[kk] = (short)h2; l1[kk] = (short)f2bf(y - bf2f(h2));
    }
    size_t off = (size_t)(nb + n) * K + kb + k0;
    *(bf16x8*)&Thi[off]     = h0;
    *(bf16x8*)&Thi[off + 8] = h1;
    *(bf16x8*)&Tlo[off]     = l0;
    *(bf16x8*)&Tlo[off + 8] = l1;
}

// ---------------------------------------------------------------------------
// Split-bf16 MFMA GEMM (validated round 6). 128x128 tile, BK=32,
// 4 waves x (64x64), global_load_lds staging, 3 MFMAs per fragment pair.
// MODE 0: scatter bf16 q(*SCALE)/k [B][H][N][D], v^T [B][H][D][N]
// MODE 1: + bias, fp32 store to out[M][N]
// ---------------------------------------------------------------------------
template <int MODE>
__global__ __launch_bounds__(256) void gemm_split_kernel(
    const u16* __restrict__ Ahi, const u16* __restrict__ Alo,
    const u16* __restrict__ Bhi, const u16* __restrict__ Blo,
    const float* __restrict__ bias,
    float* __restrict__ outf, u16* __restrict__ outb,
    int M, int N, int K)
{
    __shared__ __align__(16) u16 lds[4][128 * 32];   // Ahi, Alo, BhiT, BloT

    const int bm   = blockIdx.y * 128;
    const int bn   = blockIdx.x * 128;
    const int tid  = threadIdx.x;
    const int wid  = tid >> 6;
    const int lane = tid & 63;
    const int lo   = lane & 15;
    const int g4   = lane >> 4;
    const int wr   = wid >> 1, wc = wid & 1;

    const int mrow = lane >> 2;
    const int ks8  = (lane & 3) * 8;
    const u16* g0;
    if      (wid == 0) g0 = Ahi + (size_t)(bm + mrow) * K + ks8;
    else if (wid == 1) g0 = Alo + (size_t)(bm + mrow) * K + ks8;
    else if (wid == 2) g0 = Bhi + (size_t)(bn + mrow) * K + ks8;
    else               g0 = Blo + (size_t)(bn + mrow) * K + ks8;
    u16* lbase = &lds[wid][0];

    f32x4 acc[4][4] = {};

    for (int k0 = 0; k0 < K; k0 += 32) {
        const u16* g = g0 + k0;
        #pragma unroll
        for (int s = 0; s < 8; ++s)
            gload_lds16(g + (size_t)s * 16 * K, lbase + s * 512);
        __syncthreads();

        bf16x8 bh[4], bl[4];
        #pragma unroll
        for (int ni = 0; ni < 4; ++ni) {
            int row = wc * 64 + ni * 16 + lo;
            bh[ni] = *(const bf16x8*)&lds[2][row * 32 + g4 * 8];
            bl[ni] = *(const bf16x8*)&lds[3][row * 32 + g4 * 8];
        }
        #pragma unroll
        for (int mi = 0; mi < 4; ++mi) {
            int row = wr * 64 + mi * 16 + lo;
            bf16x8 ah = *(const bf16x8*)&lds[0][row * 32 + g4 * 8];
            bf16x8 al = *(const bf16x8*)&lds[1][row * 32 + g4 * 8];
            #pragma unroll
            for (int ni = 0; ni < 4; ++ni) {
                acc[mi][ni] = __builtin_amdgcn_mfma_f32_16x16x32_bf16(ah, bh[ni], acc[mi][ni], 0, 0, 0);
                acc[mi][ni] = __builtin_amdgcn_mfma_f32_16x16x32_bf16(ah, bl[ni], acc[mi][ni], 0, 0, 0);
                acc[mi][ni] = __builtin_amdgcn_mfma_f32_16x16x32_bf16(al, bh[ni], acc[mi][ni], 0, 0, 0);
            }
        }
        __syncthreads();
    }

    if (MODE == 0) {
        #pragma unroll
        for (int mi = 0; mi < 4; ++mi) {
            int m0 = bm + wr * 64 + mi * 16 + 4 * g4;
            #pragma unroll
            for (int ni = 0; ni < 4; ++ni) {
                int n0    = bn + wc * 64 + ni * 16;
                int which = n0 >> 10;
                int head  = (n0 & 1023) >> 6;
                int d     = (n0 & 63) + lo;
                if (which == 0) {
                    #pragma unroll
                    for (int r = 0; r < 4; ++r) {
                        int m = m0 + r, b = m >> 11, seq = m & 2047;
                        outb[(((size_t)b * NHEADS + head) * SEQ + seq) * HDIM + d] =
                            f2bf(acc[mi][ni][r] * SCALE);
                    }
                } else if (which == 1) {
                    #pragma unroll
                    for (int r = 0; r < 4; ++r) {
                        int m = m0 + r, b = m >> 11, seq = m & 2047;
                        outb[BHND + (((size_t)b * NHEADS + head) * SEQ + seq) * HDIM + d] =
                            f2bf(acc[mi][ni][r]);
                    }
                } else {
                    int b = m0 >> 11, seq0 = m0 & 2047;
                    ushort4 o;
                    o.x = f2bf(acc[mi][ni][0]); o.y = f2bf(acc[mi][ni][1]);
                    o.z = f2bf(acc[mi][ni][2]); o.w = f2bf(acc[mi][ni][3]);
                    *(ushort4*)&outb[2 * BHND +
                        (((size_t)b * NHEADS + head) * HDIM + d) * SEQ + seq0] = o;
                }
            }
        }
    } else {
        #pragma unroll
        for (int ni = 0; ni < 4; ++ni) {
            int col = bn + wc * 64 + ni * 16 + lo;
            float bv = bias[col];
            #pragma unroll
            for (int mi = 0; mi < 4; ++mi) {
                int m0 = bm + wr * 64 + mi * 16 + 4 * g4;
                #pragma unroll
                for (int r = 0; r < 4; ++r)
                    outf[(size_t)(m0 + r) * N + col] = acc[mi][ni][r] + bv;
            }
        }
    }
}

// ---------------------------------------------------------------------------
// MFMA flash attention, KVBLK=64, SWAPPED QK^T: S^T = mfma(K, Q) puts the
// whole S-row for q = lane&15 in-lane -> softmax is 30 in-lane ops + 4
// shfl_xor per 64-key tile (was ~16 bpermutes). m/l are scalars; corr/inv
// pulled to the acc layout (q = 4g+r) by 4 shuffles only on rescale/epilogue.
// Round-7 XOR-swizzled K/V staging (measured 1.05M conflicts). P packed as
// ushort4 b64 stores. Split-bf16 O epilogue.
// ---------------------------------------------------------------------------
__global__ __launch_bounds__(256) void attn_mfma_kernel(
    const u16* __restrict__ qb, const u16* __restrict__ kb,
    const u16* __restrict__ vtb, const float* __restrict__ mask,
    u16* __restrict__ ohi, u16* __restrict__ olo)
{
    __shared__ __align__(16) u16 Ks[64 * 64];       // [key][d] swizzled
    __shared__ __align__(16) u16 Vt[64 * 64];       // [d][key] swizzled
    __shared__ __align__(16) u16 Plds[4][16 * 72];  // [wave][q][key], pad 72
    __shared__ float Ms[64];

    const int bid  = blockIdx.x;          // 1024 = B*H*(SEQ/64)
    const int qt   = bid & 31;
    const int h    = (bid >> 5) & 15;
    const int b    = bid >> 9;
    const int tid  = threadIdx.x;
    const int wid  = tid >> 6;
    const int lane = tid & 63;
    const int lo   = lane & 15;
    const int g    = lane >> 4;

    const size_t bh = (size_t)b * NHEADS + h;
    const int qbase = qt * 64 + wid * 16;

    // Q fragment (B operand of swapped QK^T): col = q = qbase+lo, k = 32ks+8g+j
    const u16* qrowp = qb + (bh * SEQ + qbase + lo) * HDIM + 8 * g;
    const bf16x8 aq0 = *(const bf16x8*)(qrowp);
    const bf16x8 aq1 = *(const bf16x8*)(qrowp + 32);

    // staging: 64x64 tiles, thread -> row = tid>>2, two 8-elem slots (round 7)
    const int srow  = tid >> 2;
    const int scol  = (tid & 3) * 16;
    const int swz   = (srow & 7) << 3;
    const int idx0  = srow * 64 + (scol ^ swz);
    const int idx1  = srow * 64 + ((scol + 8) ^ swz);
    const u16* kgp  = kb  + (bh * SEQ  + srow) * HDIM + scol;   // + k0*HDIM
    const u16* vgp  = vtb + (bh * HDIM + srow) * SEQ  + scol;   // + k0

    f32x4 acc[4] = {};            // O[q = 4g+r][d = 16dt+lo]
    float mrun = -1e30f, lrun = 0.f;   // softmax state for q = lo

    u16* pw = &Plds[wid][0];

    for (int k0 = 0; k0 < SEQ; k0 += 64) {
        __syncthreads();
        *(bf16x8*)&Ks[idx0] = *(const bf16x8*)(kgp + (size_t)k0 * HDIM);
        *(bf16x8*)&Ks[idx1] = *(const bf16x8*)(kgp + (size_t)k0 * HDIM + 8);
        *(bf16x8*)&Vt[idx0] = *(const bf16x8*)(vgp + k0);
        *(bf16x8*)&Vt[idx1] = *(const bf16x8*)(vgp + k0 + 8);
        if (tid < 64) Ms[tid] = mask[b * SEQ + k0 + tid];
        __syncthreads();

        // swapped QK^T: s[kt][r] = S[key = 16kt+4g+r][q = lo]
        f32x4 s[4];
        #pragma unroll
        for (int kt = 0; kt < 4; ++kt) {
            int key  = lo + 16 * kt;            // A-frag row = key
            int kbse = key * 64;
            int ksw  = (key & 7) << 3;
            f32x4 t = {};
            t = __builtin_amdgcn_mfma_f32_16x16x32_bf16(*(const bf16x8*)&Ks[kbse + ((8 * g) ^ ksw)], aq0, t, 0, 0, 0);
            t = __builtin_amdgcn_mfma_f32_16x16x32_bf16(*(const bf16x8*)&Ks[kbse + ((32 + 8 * g) ^ ksw)], aq1, t, 0, 0, 0);
            s[kt] = t;
        }

        // mask values for this lane's keys: Ms[16kt + 4g + r]
        f32x4 mv[4];
        #pragma unroll
        for (int kt = 0; kt < 4; ++kt)
            mv[kt] = *(const f32x4*)&Ms[16 * kt + 4 * g];

        // row softmax for q = lo, fully in-lane + 2+2 shfl_xor
        float rm = s[0][0];
        #pragma unroll
        for (int kt = 0; kt < 4; ++kt)
            #pragma unroll
            for (int r = 0; r < 4; ++r) rm = fmaxf(rm, s[kt][r]);
        rm = fmaxf(rm, __shfl_xor(rm, 16));
        rm = fmaxf(rm, __shfl_xor(rm, 32));

        if (!__all(rm <= mrun)) {            // bit-exact skip (corr==1 if skipped)
            float mnew = fmaxf(mrun, rm);
            float corr = __expf(mrun - mnew);
            mrun = mnew;
            lrun *= corr;
            #pragma unroll
            for (int r = 0; r < 4; ++r) {
                float cq = __shfl(corr, 4 * g + r);   // corr for q = 4g+r
                #pragma unroll
                for (int dt = 0; dt < 4; ++dt) acc[dt][r] *= cq;
            }
        }

        float ps = 0.f;
        float p[4][4];
        #pragma unroll
        for (int kt = 0; kt < 4; ++kt)
            #pragma unroll
            for (int r = 0; r < 4; ++r) {
                p[kt][r] = __expf(s[kt][r] - mrun);
                ps += p[kt][r];              // UNMASKED denominator
            }
        ps += __shfl_xor(ps, 16);
        ps += __shfl_xor(ps, 32);
        lrun += ps;

        // masked numerator -> P in LDS, packed b64 stores (A-frag layout)
        #pragma unroll
        for (int kt = 0; kt < 4; ++kt) {
            ushort4 o;
            o.x = f2bf(p[kt][0] * mv[kt][0]);
            o.y = f2bf(p[kt][1] * mv[kt][1]);
            o.z = f2bf(p[kt][2] * mv[kt][2]);
            o.w = f2bf(p[kt][3] * mv[kt][3]);
            *(ushort4*)&pw[lo * 72 + 16 * kt + 4 * g] = o;
        }

        // PV: O += P[16,64] @ V[64,64]   (same-wave DS ops are in-order)
        const bf16x8 pa0 = *(const bf16x8*)&pw[lo * 72 + 8 * g];
        const bf16x8 pa1 = *(const bf16x8*)&pw[lo * 72 + 32 + 8 * g];
        #pragma unroll
        for (int dt = 0; dt < 4; ++dt) {
            int vbse = (lo + 16 * dt) * 64;
            int vsw  = (lo & 7) << 3;
            acc[dt] = __builtin_amdgcn_mfma_f32_16x16x32_bf16(pa0, *(const bf16x8*)&Vt[vbse + ((8 * g) ^ vsw)], acc[dt], 0, 0, 0);
            acc[dt] = __builtin_amdgcn_mfma_f32_16x16x32_bf16(pa1, *(const bf16x8*)&Vt[vbse + ((32 + 8 * g) ^ vsw)], acc[dt], 0, 0, 0);
        }
    }

    // epilogue: pull 1/l to the acc layout, split bf16 O for the proj GEMM
    const float inv = 1.f / lrun;
    #pragma unroll
    for (int r = 0; r < 4; ++r) {
        float invq = __shfl(inv, 4 * g + r);
        size_t row = (size_t)b * SEQ + qbase + 4 * g + r;
        u16* dh = ohi + row * DIMC + h * HDIM + lo;
        u16* dl = olo + row * DIMC + h * HDIM + lo;
        #pragma unroll
        for (int dt = 0; dt < 4; ++dt) {
            float o = acc[dt][r] * invq;
            u16 hv = f2bf(o);
            dh[16 * dt] = hv;
            dl[16 * dt] = f2bf(o - bf2f(hv));
        }
    }
}

__global__ void mask_sqrt_kernel(const float* __restrict__ mask,
                                 float* __restrict__ out, int n)
{
    int i = blockIdx.x * 256 + threadIdx.x;
    if (i < n) out[i] = sqrtf(mask[i]);
}

// ---------------------------------------------------------------------------
extern "C" void kernel_launch(void* const* d_in, const int* in_sizes, int n_in,
                              void* d_out, int out_size, void* d_ws, size_t ws_size,
                              hipStream_t stream)
{
    const float* h      = (const float*)d_in[0];   // [2,2048,1024]
    const float* mask   = (const float*)d_in[1];   // [2,2048]
    const float* w_qkv  = (const float*)d_in[2];   // [1024,3072]
    const float* w_proj = (const float*)d_in[3];   // [1024,1024]
    const float* b_proj = (const float*)d_in[4];   // [1024]
    float* out = (float*)d_out;

    // ws layout (u16 units), ~59 MB total
    u16* w    = (u16*)d_ws;
    u16* qkv  = w;                                  // 3*BHND
    u16* wqh  = qkv + 3 * BHND;                     // 3072*1024
    u16* wql  = wqh + (size_t)3072 * 1024;
    u16* wph  = wql + (size_t)3072 * 1024;          // 1024*1024
    u16* wpl  = wph + (size_t)1024 * 1024;
    u16* ahi  = wpl + (size_t)1024 * 1024;          // 4096*1024 (h split; later O split)
    u16* alo  = ahi + MROWS * DIMC;

    // prepasses: split h; split+transpose weights
    splita_kernel<<<(MROWS * DIMC) / (256 * 8), 256, 0, stream>>>(h, ahi, alo);
    splitw_kernel<<<dim3(16, 48), 256, 0, stream>>>(w_qkv, wqh, wql, DIMC, 3 * DIMC);
    splitw_kernel<<<dim3(16, 16), 256, 0, stream>>>(w_proj, wph, wpl, DIMC, DIMC);

    // 1) qkv projection (split MFMA) -> bf16 q(scaled)/k [B][H][N][D], v^T [B][H][D][N]
    gemm_split_kernel<0><<<dim3(24, 32), 256, 0, stream>>>(
        ahi, alo, wqh, wql, nullptr, nullptr, qkv, MROWS, 3 * DIMC, DIMC);

    // 2) MFMA flash attention (KVBLK=64, swapped QK^T) -> split O
    attn_mfma_kernel<<<BATCH * NHEADS * (SEQ / 64), 256, 0, stream>>>(
        qkv, qkv + BHND, qkv + 2 * BHND, mask, ahi, alo);

    // 3) output projection + bias (split MFMA, fp32 out)
    gemm_split_kernel<1><<<dim3(8, 32), 256, 0, stream>>>(
        ahi, alo, wph, wpl, b_proj, out, nullptr, MROWS, DIMC, DIMC);

    // 4) new_mask = sqrt(mask)
    mask_sqrt_kernel<<<(BATCH * SEQ + 255) / 256, 256, 0, stream>>>(
        mask, out + MROWS * DIMC, BATCH * SEQ);
}